// Round 9
// baseline (245.374 us; speedup 1.0000x reference)
//
#include <hip/hip_runtime.h>
#include <hip/hip_bf16.h>

typedef __attribute__((ext_vector_type(8))) short short8;
typedef __attribute__((ext_vector_type(4))) float float4v;
typedef _Float16 half4v __attribute__((ext_vector_type(4)));

#define NB 32
#define LL 128
#define DDIM 300
#define DP 320
#define KDIM 50
#define WP 328   // wtile pitch (bf16 elems)
#define TP 40    // Tt pitch
#define SLAB_OFF 18759680ull
#define SLAB_BYTES (50ull * 32ull * 16384ull * 2ull)          // 52,428,800
#define WS_NEED  (SLAB_OFF + SLAB_BYTES)

__device__ __forceinline__ unsigned short f2bf(float x) {
    unsigned int u = __float_as_uint(x);
    unsigned int r = (u + 0x7FFFu + ((u >> 16) & 1u)) >> 16;
    return (unsigned short)r;
}
__device__ __forceinline__ unsigned int pack2bf(float a, float b) {
    return (unsigned int)f2bf(a) | ((unsigned int)f2bf(b) << 16);
}
__device__ __forceinline__ float4v mfma16(short8 a, short8 b, float4v c) {
    return __builtin_amdgcn_mfma_f32_16x16x32_bf16(a, b, c, 0, 0, 0);
}

// ---------- fused prep: [0,500) Wb->Wbt arm; [500,1012) projections+convert arm ----------
__global__ void prep_all(const float* __restrict__ e1, const float* __restrict__ e2,
                         const float* __restrict__ Wb,
                         const float* __restrict__ Wd, const float* __restrict__ Wg,
                         unsigned short* __restrict__ e1b, unsigned short* __restrict__ e2b,
                         unsigned short* __restrict__ wbt,
                         float* __restrict__ p1d, float* __restrict__ p1g,
                         float* __restrict__ p2d, float* __restrict__ p2g) {
    const int blk = blockIdx.x;
    __shared__ float tile[32][33];

    if (blk < 500) {
        // ---- Wb transpose arm: (k, e-tile), dt loop inside ----
        int k = blk / 10, et = blk % 10;
        int tx = threadIdx.x & 31, ty = threadIdx.x >> 5;
        for (int dt = 0; dt < 10; ++dt) {
#pragma unroll
            for (int rr = 0; rr < 4; ++rr) {
                int d = dt * 32 + ty + rr * 8;
                int e = et * 32 + tx;
                tile[ty + rr * 8][tx] = (d < DDIM && e < DDIM) ? Wb[((size_t)k * DDIM + d) * DDIM + e] : 0.f;
            }
            __syncthreads();
#pragma unroll
            for (int rr = 0; rr < 4; ++rr) {
                int e = et * 32 + ty + rr * 8;
                int d = dt * 32 + tx;
                wbt[((size_t)k * DP + e) * DP + d] = f2bf(tile[tx][ty + rr * 8]);
            }
            __syncthreads();
        }
        return;
    }
    // ---- projection + conversion arm: 512 blocks, 16 rows each ----
    int bid = blk - 500;
    const int kk = threadIdx.x & 63;
    const int grp = threadIdx.x >> 6;
    const int kks = kk < KDIM ? kk : 0;
    const float* src; int woff; float *dd, *dg; int r0;
    unsigned short* bdst;
    int rowbase = bid * 16;
    if (rowbase < 4096) { r0 = rowbase; src = e1; woff = 0; dd = p1d; dg = p1g; bdst = e1b; }
    else { r0 = rowbase - 4096; src = e2; woff = DDIM; dd = p2d; dg = p2g; bdst = e2b; }
    const float* e0 = src + (size_t)(r0 + grp * 4) * DDIM;
    const float* wdp = Wd + (size_t)woff * KDIM + kks;
    const float* wgp = Wg + (size_t)woff * KDIM + kks;

    float ad[4] = {0.f, 0.f, 0.f, 0.f}, ag[4] = {0.f, 0.f, 0.f, 0.f};
    for (int c = 0; c < DDIM / 4; ++c) {
        const int d0 = c * 4;
        float4 x[4];
#pragma unroll
        for (int rr = 0; rr < 4; ++rr)
            x[rr] = *(const float4*)(e0 + (size_t)rr * DDIM + d0);
        float wd0 = wdp[(size_t)(d0 + 0) * KDIM];
        float wd1 = wdp[(size_t)(d0 + 1) * KDIM];
        float wd2 = wdp[(size_t)(d0 + 2) * KDIM];
        float wd3 = wdp[(size_t)(d0 + 3) * KDIM];
        float wg0 = wgp[(size_t)(d0 + 0) * KDIM];
        float wg1 = wgp[(size_t)(d0 + 1) * KDIM];
        float wg2 = wgp[(size_t)(d0 + 2) * KDIM];
        float wg3 = wgp[(size_t)(d0 + 3) * KDIM];
#pragma unroll
        for (int rr = 0; rr < 4; ++rr) {
            ad[rr] += x[rr].x * wd0 + x[rr].y * wd1 + x[rr].z * wd2 + x[rr].w * wd3;
            ag[rr] += x[rr].x * wg0 + x[rr].y * wg1 + x[rr].z * wg2 + x[rr].w * wg3;
        }
    }
    if (kk < KDIM) {
#pragma unroll
        for (int rr = 0; rr < 4; ++rr) {
            size_t o = (size_t)(r0 + grp * 4 + rr) * KDIM + kk;
            dd[o] = ad[rr];
            dg[o] = ag[rr];
        }
    }
    // conversion: this block's 16 rows -> bf16 padded (640 granules of 8)
    for (int it = 0; it < 3; ++it) {
        int g = threadIdx.x + it * 256;
        if (g >= 640) break;
        int rl = g / 40, d0 = (g % 40) * 8;
        const float* sp = src + (size_t)(r0 + rl) * DDIM;
        unsigned short* dp = bdst + (size_t)(r0 + rl) * DP + d0;
        float v[8];
        if (d0 + 8 <= DDIM) {
            float4 lo = *(const float4*)(sp + d0);
            float4 hi = *(const float4*)(sp + d0 + 4);
            v[0] = lo.x; v[1] = lo.y; v[2] = lo.z; v[3] = lo.w;
            v[4] = hi.x; v[5] = hi.y; v[6] = hi.z; v[7] = hi.w;
        } else if (d0 < DDIM) {          // d0 == 296
            float4 lo = *(const float4*)(sp + d0);
            v[0] = lo.x; v[1] = lo.y; v[2] = lo.z; v[3] = lo.w;
            v[4] = v[5] = v[6] = v[7] = 0.f;
        } else {
            for (int j = 0; j < 8; ++j) v[j] = 0.f;
        }
        unsigned short tmp[8];
#pragma unroll
        for (int j = 0; j < 8; ++j) tmp[j] = f2bf(v[j]);
        *(short8*)dp = *(short8*)tmp;
    }
}

// ---------- main: per (b,k): S = (e1 Wb[k]) e2^T, gate ----------
// LDS holds only wtile + T; e2 phase-2 fragments are prefetched global->regs
// (wave-invariant addresses -> L1-served; latency covered by phase-1 compute).
template <int SLAB>
__global__ __launch_bounds__(256, 2) void grn_main(
    const unsigned short* __restrict__ e1b, const unsigned short* __restrict__ e2b,
    const unsigned short* __restrict__ wbt,
    const float* __restrict__ p1d, const float* __restrict__ p1g,
    const float* __restrict__ p2d, const float* __restrict__ p2g,
    const float* __restrict__ bg, const float* __restrict__ bb,
    const float* __restrict__ u, float* __restrict__ out, _Float16* __restrict__ slab) {
    const int b = blockIdx.x, k = blockIdx.y;
    const int tid = threadIdx.x;
    const int wid = tid >> 6, lane = tid & 63;
    const int q = lane >> 4, ln = lane & 15;
    const int rw0 = wid * 32;                      // wave owns i-rows [rw0, rw0+32)

    __shared__ __align__(16) unsigned short wtile[32 * WP];   // Wbt tile [e'][d], 20992B
    __shared__ __align__(16) unsigned short Tt[128 * TP];     // T tile   [i][e'], 10240B
    __shared__ float pbuf[4][128];                            // 2048B

    if (tid < 128) {
        int gi = (b * LL + tid) * KDIM + k;
        pbuf[0][tid] = p1d[gi];
        pbuf[1][tid] = p1g[gi];
        pbuf[2][tid] = p2d[gi];
        pbuf[3][tid] = p2g[gi];
    }
    const float u_k = u[k], bg_k = bg[k], b_k = bb[k];

    const unsigned short* wbt_k = wbt + (size_t)k * DP * DP;
    size_t wgo[5]; int wlo[5];
#pragma unroll
    for (int it = 0; it < 5; ++it) {
        int c = tid + it * 256, r = c / 40, col = (c % 40) * 8;
        wgo[it] = (size_t)r * DP + col;
        wlo[it] = r * WP + col;
    }

    // e1 B-fragments: lane holds e1[i=rw0+mt*16+ln][d=kd*32+q*8+j]; reused 10x
    short8 af[2][10];
#pragma unroll
    for (int mt = 0; mt < 2; ++mt) {
        const unsigned short* p = e1b + ((size_t)(b * LL + rw0 + mt * 16 + ln)) * DP + q * 8;
#pragma unroll
        for (int kd = 0; kd < 10; ++kd)
            af[mt][kd] = *(const short8*)(p + kd * 32);
    }

    float4v S[2][8];
#pragma unroll
    for (int mt = 0; mt < 2; ++mt)
#pragma unroll
        for (int nt = 0; nt < 8; ++nt)
            S[mt][nt] = (float4v){0.f, 0.f, 0.f, 0.f};

    // e2 phase-2 fragment base: lane (q,ln) covers e2[j=nt*16+ln][e0 + q*8..q*8+7]
    const unsigned short* ebase = e2b + ((size_t)(b * LL + ln)) * DP + q * 8;

    // prefetch tile 0: wtile staging regs + e2 fragments
    short8 wpre[5], ef[8];
#pragma unroll
    for (int it = 0; it < 5; ++it) wpre[it] = *(const short8*)(wbt_k + wgo[it]);
#pragma unroll
    for (int nt = 0; nt < 8; ++nt) ef[nt] = *(const short8*)(ebase + (size_t)(nt * 16) * DP);

    char* twr = (char*)Tt + (rw0 + ln) * 80;

    for (int et = 0; et < 10; ++et) {
#pragma unroll
        for (int it = 0; it < 5; ++it) *(short8*)&wtile[wlo[it]] = wpre[it];
        __syncthreads();

        if (et < 9) {
            const size_t ew = (size_t)(et + 1) * 32 * DP;
#pragma unroll
            for (int it = 0; it < 5; ++it) wpre[it] = *(const short8*)(wbt_k + ew + wgo[it]);
        }

        // phase 1: T[e'][i] = sum_d Wb[e'][d]*e1[i][d]; A=wtile rows e', B=af rows i
        float4v tacc[2][2];   // [emt][imt]
#pragma unroll
        for (int emt = 0; emt < 2; ++emt)
#pragma unroll
            for (int imt = 0; imt < 2; ++imt)
                tacc[emt][imt] = (float4v){0.f, 0.f, 0.f, 0.f};
#pragma unroll
        for (int kd = 0; kd < 10; ++kd) {
            short8 wa0 = *(const short8*)&wtile[(ln) * WP + kd * 32 + q * 8];
            short8 wa1 = *(const short8*)&wtile[(16 + ln) * WP + kd * 32 + q * 8];
            tacc[0][0] = mfma16(wa0, af[0][kd], tacc[0][0]);
            tacc[0][1] = mfma16(wa0, af[1][kd], tacc[0][1]);
            tacc[1][0] = mfma16(wa1, af[0][kd], tacc[1][0]);
            tacc[1][1] = mfma16(wa1, af[1][kd], tacc[1][1]);
        }
        // T write: tacc[emt][imt][r] = T[e'=emt*16+q*4+r][i=rw0+imt*16+ln]
        //  -> Tt[i][e'], one b64 per (imt,emt); wave-private rows
#pragma unroll
        for (int imt = 0; imt < 2; ++imt) {
            char* tw = twr + imt * (16 * 80) + q * 8;
#pragma unroll
            for (int emt = 0; emt < 2; ++emt) {
                uint2 v;
                v.x = pack2bf(tacc[emt][imt][0], tacc[emt][imt][1]);
                v.y = pack2bf(tacc[emt][imt][2], tacc[emt][imt][3]);
                *(uint2*)(tw + emt * 32) = v;
            }
        }
        // phase 2: S[i][j] += sum_e' T[i][e'] * e2[j][e']  (e2 frags in regs)
        short8 a0 = *(const short8*)(twr + q * 16);
        short8 a1 = *(const short8*)(twr + 16 * 80 + q * 16);
#pragma unroll
        for (int nt = 0; nt < 8; ++nt) {
            S[0][nt] = mfma16(a0, ef[nt], S[0][nt]);
            S[1][nt] = mfma16(a1, ef[nt], S[1][nt]);
        }
        // reload e2 fragments for next tile (latency hidden by next phase 1)
        if (et < 9) {
            const int ee = (et + 1) * 32;
#pragma unroll
            for (int nt = 0; nt < 8; ++nt)
                ef[nt] = *(const short8*)(ebase + (size_t)(nt * 16) * DP + ee);
        }
        __syncthreads();
    }

    // epilogue: gate, mix, scale by u[k]
    float pdi[2][4], pgi[2][4];
#pragma unroll
    for (int mt = 0; mt < 2; ++mt)
#pragma unroll
        for (int r = 0; r < 4; ++r) {
            int i = rw0 + mt * 16 + q * 4 + r;
            pdi[mt][r] = pbuf[0][i];
            pgi[mt][r] = pbuf[1][i];
        }
    _Float16* sdst = slab + ((size_t)k * NB + b) * 16384;
    float* adst = out + (size_t)b * LL * LL;
#pragma unroll
    for (int nt = 0; nt < 8; ++nt) {
        int j = nt * 16 + ln;
        float pdj = pbuf[2][j];
        float pgj = pbuf[3][j] + bg_k;
#pragma unroll
        for (int mt = 0; mt < 2; ++mt)
#pragma unroll
            for (int r = 0; r < 4; ++r) {
                int i = rw0 + mt * 16 + q * 4 + r;
                float btp = S[mt][nt][r];
                float sd = pdi[mt][r] + pdj;
                float sg = pgi[mt][r] + pgj;
                float e2x = __expf(2.f * sd);
                float sln = 1.f - 2.f * __builtin_amdgcn_rcpf(e2x + 1.f);   // tanh(sd)
                float g = __builtin_amdgcn_rcpf(1.f + __expf(-sg));          // sigmoid(sg)
                float val = u_k * (g * btp + (1.f - g) * sln + b_k);
                if (SLAB) {
                    // permuted coalesced layout: pos = v*256 + tid, v = nt*8+mt*4+r
                    sdst[(nt * 8 + mt * 4 + r) * 256 + tid] = (_Float16)val;
                } else {
                    unsafeAtomicAdd(adst + (size_t)i * LL + j, val);
                }
            }
    }
}

// ---------- reduce: out[b][i][j] = sum_k slab[k][b][pos]; decode permutation ----------
__global__ void reduce_k(const _Float16* __restrict__ slab, float* __restrict__ out) {
    int idx = blockIdx.x * 256 + threadIdx.x;     // 0..131071
    int b = idx >> 12;
    int p4 = idx & 4095;
    int pos0 = p4 * 4;
    int v = pos0 >> 8, tid0 = pos0 & 255;
    int nt = v >> 3, mt = (v >> 2) & 1, r = v & 3;
    int wid = tid0 >> 6, q = (tid0 >> 4) & 3, ln0 = tid0 & 15;
    int i = wid * 32 + mt * 16 + q * 4 + r;
    int j0 = nt * 16 + ln0;

    float a0 = 0.f, a1 = 0.f, a2 = 0.f, a3 = 0.f;
    const _Float16* sp = slab + (size_t)b * 16384 + pos0;
#pragma unroll
    for (int k = 0; k < KDIM; ++k) {
        half4v h = *(const half4v*)(sp + (size_t)k * (NB * 16384));
        a0 += (float)h[0]; a1 += (float)h[1]; a2 += (float)h[2]; a3 += (float)h[3];
    }
    float4 rv; rv.x = a0; rv.y = a1; rv.z = a2; rv.w = a3;
    *(float4*)(out + (size_t)b * 16384 + i * 128 + j0) = rv;
}

extern "C" void kernel_launch(void* const* d_in, const int* in_sizes, int n_in,
                              void* d_out, int out_size, void* d_ws, size_t ws_size,
                              hipStream_t stream) {
    const float* e1 = (const float*)d_in[0];   // (32,128,300)
    const float* e2 = (const float*)d_in[1];   // (32,128,300)
    const float* Wb = (const float*)d_in[2];   // (50,300,300)
    const float* Wd = (const float*)d_in[3];   // (600,50)
    const float* Wg = (const float*)d_in[4];   // (600,50)
    const float* bg = (const float*)d_in[5];   // (50,)
    const float* bb = (const float*)d_in[6];   // (50,)
    const float* u  = (const float*)d_in[7];   // (50,1)
    float* out = (float*)d_out;                // (32,128,128,1)

    unsigned short* e1b = (unsigned short*)d_ws;                 // 1,310,720 elems
    unsigned short* e2b = e1b + 1310720;                         // 1,310,720 elems
    unsigned short* wbt = e2b + 1310720;                         // 5,120,000 elems
    float* pf  = (float*)((char*)d_ws + 15482880);
    float* p1d = pf;
    float* p1g = pf + 204800;
    float* p2d = pf + 409600;
    float* p2g = pf + 614400;                                    // end 18,759,680 B
    _Float16* slab = (_Float16*)((char*)d_ws + SLAB_OFF);        // 50x32x16384 halves

    prep_all<<<1012, 256, 0, stream>>>(e1, e2, Wb, Wd, Wg,
                                       e1b, e2b, wbt,
                                       p1d, p1g, p2d, p2g);

    if (ws_size >= WS_NEED) {
        grn_main<1><<<dim3(NB, KDIM), 256, 0, stream>>>(e1b, e2b, wbt,
                                                        p1d, p1g, p2d, p2g,
                                                        bg, bb, u, out, slab);
        reduce_k<<<512, 256, 0, stream>>>(slab, out);
    } else {
        hipMemsetAsync(d_out, 0, (size_t)out_size * sizeof(float), stream);
        grn_main<0><<<dim3(NB, KDIM), 256, 0, stream>>>(e1b, e2b, wbt,
                                                        p1d, p1g, p2d, p2g,
                                                        bg, bb, u, out, slab);
    }
}

// Round 10
// 218.306 us; speedup vs baseline: 1.1240x; 1.1240x over previous
//
#include <hip/hip_runtime.h>
#include <hip/hip_bf16.h>

typedef __attribute__((ext_vector_type(8))) short short8;
typedef __attribute__((ext_vector_type(4))) float float4v;
typedef __attribute__((ext_vector_type(16))) float float16v;
typedef _Float16 half4v __attribute__((ext_vector_type(4)));

#define NB 32
#define LL 128
#define DDIM 300
#define DP 320
#define KDIM 50
#define WP 328   // wtile pitch (bf16 elems)
#define TP 40    // Tt/e2t pitch
#define SLAB_OFF 18759680ull
#define SLAB_BYTES (50ull * 32ull * 16384ull * 2ull)          // 52,428,800
#define WS_NEED  (SLAB_OFF + SLAB_BYTES)

__device__ __forceinline__ unsigned short f2bf(float x) {
    unsigned int u = __float_as_uint(x);
    unsigned int r = (u + 0x7FFFu + ((u >> 16) & 1u)) >> 16;
    return (unsigned short)r;
}
__device__ __forceinline__ unsigned int pack2bf(float a, float b) {
    return (unsigned int)f2bf(a) | ((unsigned int)f2bf(b) << 16);
}
__device__ __forceinline__ float4v mfma16(short8 a, short8 b, float4v c) {
    return __builtin_amdgcn_mfma_f32_16x16x32_bf16(a, b, c, 0, 0, 0);
}
__device__ __forceinline__ float16v mfma32(short8 a, short8 b, float16v c) {
    return __builtin_amdgcn_mfma_f32_32x32x16_bf16(a, b, c, 0, 0, 0);
}

// ---------- fused prep: [0,500) Wb->Wbt arm; [500,1012) projections+convert arm ----------
__global__ void prep_all(const float* __restrict__ e1, const float* __restrict__ e2,
                         const float* __restrict__ Wb,
                         const float* __restrict__ Wd, const float* __restrict__ Wg,
                         unsigned short* __restrict__ e1b, unsigned short* __restrict__ e2b,
                         unsigned short* __restrict__ wbt,
                         float* __restrict__ p1d, float* __restrict__ p1g,
                         float* __restrict__ p2d, float* __restrict__ p2g) {
    const int blk = blockIdx.x;
    __shared__ float tile[32][33];

    if (blk < 500) {
        // ---- Wb transpose arm: (k, e-tile), dt loop inside ----
        int k = blk / 10, et = blk % 10;
        int tx = threadIdx.x & 31, ty = threadIdx.x >> 5;
        for (int dt = 0; dt < 10; ++dt) {
#pragma unroll
            for (int rr = 0; rr < 4; ++rr) {
                int d = dt * 32 + ty + rr * 8;
                int e = et * 32 + tx;
                tile[ty + rr * 8][tx] = (d < DDIM && e < DDIM) ? Wb[((size_t)k * DDIM + d) * DDIM + e] : 0.f;
            }
            __syncthreads();
#pragma unroll
            for (int rr = 0; rr < 4; ++rr) {
                int e = et * 32 + ty + rr * 8;
                int d = dt * 32 + tx;
                wbt[((size_t)k * DP + e) * DP + d] = f2bf(tile[tx][ty + rr * 8]);
            }
            __syncthreads();
        }
        return;
    }
    // ---- projection + conversion arm: 512 blocks, 16 rows each ----
    int bid = blk - 500;
    const int kk = threadIdx.x & 63;
    const int grp = threadIdx.x >> 6;
    const int kks = kk < KDIM ? kk : 0;
    const float* src; int woff; float *dd, *dg; int r0;
    unsigned short* bdst;
    int rowbase = bid * 16;
    if (rowbase < 4096) { r0 = rowbase; src = e1; woff = 0; dd = p1d; dg = p1g; bdst = e1b; }
    else { r0 = rowbase - 4096; src = e2; woff = DDIM; dd = p2d; dg = p2g; bdst = e2b; }
    const float* e0 = src + (size_t)(r0 + grp * 4) * DDIM;
    const float* wdp = Wd + (size_t)woff * KDIM + kks;
    const float* wgp = Wg + (size_t)woff * KDIM + kks;

    float ad[4] = {0.f, 0.f, 0.f, 0.f}, ag[4] = {0.f, 0.f, 0.f, 0.f};
    for (int c = 0; c < DDIM / 4; ++c) {
        const int d0 = c * 4;
        float4 x[4];
#pragma unroll
        for (int rr = 0; rr < 4; ++rr)
            x[rr] = *(const float4*)(e0 + (size_t)rr * DDIM + d0);
        float wd0 = wdp[(size_t)(d0 + 0) * KDIM];
        float wd1 = wdp[(size_t)(d0 + 1) * KDIM];
        float wd2 = wdp[(size_t)(d0 + 2) * KDIM];
        float wd3 = wdp[(size_t)(d0 + 3) * KDIM];
        float wg0 = wgp[(size_t)(d0 + 0) * KDIM];
        float wg1 = wgp[(size_t)(d0 + 1) * KDIM];
        float wg2 = wgp[(size_t)(d0 + 2) * KDIM];
        float wg3 = wgp[(size_t)(d0 + 3) * KDIM];
#pragma unroll
        for (int rr = 0; rr < 4; ++rr) {
            ad[rr] += x[rr].x * wd0 + x[rr].y * wd1 + x[rr].z * wd2 + x[rr].w * wd3;
            ag[rr] += x[rr].x * wg0 + x[rr].y * wg1 + x[rr].z * wg2 + x[rr].w * wg3;
        }
    }
    if (kk < KDIM) {
#pragma unroll
        for (int rr = 0; rr < 4; ++rr) {
            size_t o = (size_t)(r0 + grp * 4 + rr) * KDIM + kk;
            dd[o] = ad[rr];
            dg[o] = ag[rr];
        }
    }
    // conversion: this block's 16 rows -> bf16 padded (640 granules of 8)
    for (int it = 0; it < 3; ++it) {
        int g = threadIdx.x + it * 256;
        if (g >= 640) break;
        int rl = g / 40, d0 = (g % 40) * 8;
        const float* sp = src + (size_t)(r0 + rl) * DDIM;
        unsigned short* dp = bdst + (size_t)(r0 + rl) * DP + d0;
        float v[8];
        if (d0 + 8 <= DDIM) {
            float4 lo = *(const float4*)(sp + d0);
            float4 hi = *(const float4*)(sp + d0 + 4);
            v[0] = lo.x; v[1] = lo.y; v[2] = lo.z; v[3] = lo.w;
            v[4] = hi.x; v[5] = hi.y; v[6] = hi.z; v[7] = hi.w;
        } else if (d0 < DDIM) {          // d0 == 296
            float4 lo = *(const float4*)(sp + d0);
            v[0] = lo.x; v[1] = lo.y; v[2] = lo.z; v[3] = lo.w;
            v[4] = v[5] = v[6] = v[7] = 0.f;
        } else {
            for (int j = 0; j < 8; ++j) v[j] = 0.f;
        }
        unsigned short tmp[8];
#pragma unroll
        for (int j = 0; j < 8; ++j) tmp[j] = f2bf(v[j]);
        *(short8*)dp = *(short8*)tmp;
    }
}

// ---------- main: per (b,k): S = (e1 Wb[k]) e2^T, gate ----------
// R8 dataflow (wtile+e2t staged in LDS via reg-prefetch, Tt wave-private).
// Phase 1 uses 32x32x16 MFMA: half the MFMA issues + half the address VALU
// for the same LDS traffic. Phase 2 stays 16x16x32 (Tt layout is agnostic).
template <int SLAB>
__global__ __launch_bounds__(256, 2) void grn_main(
    const unsigned short* __restrict__ e1b, const unsigned short* __restrict__ e2b,
    const unsigned short* __restrict__ wbt,
    const float* __restrict__ p1d, const float* __restrict__ p1g,
    const float* __restrict__ p2d, const float* __restrict__ p2g,
    const float* __restrict__ bg, const float* __restrict__ bb,
    const float* __restrict__ u, float* __restrict__ out, _Float16* __restrict__ slab) {
    const int b = blockIdx.x, k = blockIdx.y;
    const int tid = threadIdx.x;
    const int wid = tid >> 6, lane = tid & 63;
    const int q = lane >> 4, ln = lane & 15;
    const int l32 = lane & 31, hi = lane >> 5;     // 32x32 fragment coords
    const int rw0 = wid * 32;                      // wave owns i-rows [rw0, rw0+32)

    __shared__ __align__(16) unsigned short wtile[32 * WP];   // Wbt tile [e'][d]
    __shared__ __align__(16) unsigned short Tt[128 * TP];     // T tile   [i][e']
    __shared__ __align__(16) unsigned short e2t[128 * TP];    // e2 tile  [j][e']
    __shared__ float pbuf[4][128];

    if (tid < 128) {
        int gi = (b * LL + tid) * KDIM + k;
        pbuf[0][tid] = p1d[gi];
        pbuf[1][tid] = p1g[gi];
        pbuf[2][tid] = p2d[gi];
        pbuf[3][tid] = p2g[gi];
    }
    const float u_k = u[k], bg_k = bg[k], b_k = bb[k];

    const unsigned short* wbt_k = wbt + (size_t)k * DP * DP;
    size_t wgo[5]; int wlo[5];
#pragma unroll
    for (int it = 0; it < 5; ++it) {
        int c = tid + it * 256, r = c / 40, col = (c % 40) * 8;
        wgo[it] = (size_t)r * DP + col;
        wlo[it] = r * WP + col;
    }
    size_t ego[2]; int elo[2];
#pragma unroll
    for (int it = 0; it < 2; ++it) {
        int c = tid + it * 256, j = c >> 2, col = (c & 3) * 8;
        ego[it] = (size_t)(b * LL + j) * DP + col;
        elo[it] = j * TP + col;
    }

    // e1 B-fragments for 32x32x16: lane holds e1[i=rw0+l32][d=c*16+hi*8+j], c=0..19
    short8 af[20];
    {
        const unsigned short* p = e1b + ((size_t)(b * LL + rw0 + l32)) * DP + hi * 8;
#pragma unroll
        for (int c = 0; c < 20; ++c)
            af[c] = *(const short8*)(p + c * 16);
    }

    float4v S[2][8];
#pragma unroll
    for (int mt = 0; mt < 2; ++mt)
#pragma unroll
        for (int nt = 0; nt < 8; ++nt)
            S[mt][nt] = (float4v){0.f, 0.f, 0.f, 0.f};

    // prefetch tile 0
    short8 wpre[5], epre[2];
#pragma unroll
    for (int it = 0; it < 5; ++it) wpre[it] = *(const short8*)(wbt_k + wgo[it]);
#pragma unroll
    for (int it = 0; it < 2; ++it) epre[it] = *(const short8*)(e2b + ego[it]);

    char* twr = (char*)Tt + (rw0 + ln) * 80;        // phase-2 read base (ln 0..15)
    char* tww = (char*)Tt + (rw0 + l32) * 80;       // phase-1 write base (l32 0..31)

    for (int et = 0; et < 10; ++et) {
#pragma unroll
        for (int it = 0; it < 5; ++it) *(short8*)&wtile[wlo[it]] = wpre[it];
#pragma unroll
        for (int it = 0; it < 2; ++it) *(short8*)&e2t[elo[it]] = epre[it];
        __syncthreads();

        if (et < 9) {
            const size_t ew = (size_t)(et + 1) * 32 * DP;
            const int ee = (et + 1) * 32;
#pragma unroll
            for (int it = 0; it < 5; ++it) wpre[it] = *(const short8*)(wbt_k + ew + wgo[it]);
#pragma unroll
            for (int it = 0; it < 2; ++it) epre[it] = *(const short8*)(e2b + ego[it] + ee);
        }

        // phase 1 (32x32x16): C[m=e'][n=i] = sum_d Wb[e'][d]*e1[i][d]
        // A = wtile: lane reads row e'=l32, d = c*16 + hi*8 (16B). 2 chains.
        float16v t0, t1;
#pragma unroll
        for (int z = 0; z < 16; ++z) { t0[z] = 0.f; t1[z] = 0.f; }
#pragma unroll
        for (int c = 0; c < 20; c += 2) {
            short8 wa0 = *(const short8*)&wtile[l32 * WP + c * 16 + hi * 8];
            short8 wa1 = *(const short8*)&wtile[l32 * WP + (c + 1) * 16 + hi * 8];
            t0 = mfma32(wa0, af[c], t0);
            t1 = mfma32(wa1, af[c + 1], t1);
        }
        float16v tt = t0 + t1;
        // C layout: i = l32, e' = (r&3) + 8*(r>>2) + 4*hi  ->  Tt[i][e']
        // group g=r>>2: 4 consecutive e' at g*8+hi*4 -> one b64 each
#pragma unroll
        for (int g = 0; g < 4; ++g) {
            uint2 v;
            v.x = pack2bf(tt[g * 4 + 0], tt[g * 4 + 1]);
            v.y = pack2bf(tt[g * 4 + 2], tt[g * 4 + 3]);
            *(uint2*)(tww + g * 16 + hi * 8) = v;
        }
        // phase 2 (16x16x32): S[i][j] += sum_e' T[i][e'] * e2t[j][e']
        short8 a0 = *(const short8*)(twr + q * 16);
        short8 a1 = *(const short8*)(twr + 16 * 80 + q * 16);
#pragma unroll
        for (int nt = 0; nt < 8; ++nt) {
            short8 bf = *(const short8*)&e2t[(nt * 16 + ln) * TP + q * 8];
            S[0][nt] = mfma16(a0, bf, S[0][nt]);
            S[1][nt] = mfma16(a1, bf, S[1][nt]);
        }
        __syncthreads();
    }

    // epilogue: gate, mix, scale by u[k]
    float pdi[2][4], pgi[2][4];
#pragma unroll
    for (int mt = 0; mt < 2; ++mt)
#pragma unroll
        for (int r = 0; r < 4; ++r) {
            int i = rw0 + mt * 16 + q * 4 + r;
            pdi[mt][r] = pbuf[0][i];
            pgi[mt][r] = pbuf[1][i];
        }
    _Float16* sdst = slab + ((size_t)k * NB + b) * 16384;
    float* adst = out + (size_t)b * LL * LL;
#pragma unroll
    for (int nt = 0; nt < 8; ++nt) {
        int j = nt * 16 + ln;
        float pdj = pbuf[2][j];
        float pgj = pbuf[3][j] + bg_k;
#pragma unroll
        for (int mt = 0; mt < 2; ++mt)
#pragma unroll
            for (int r = 0; r < 4; ++r) {
                int i = rw0 + mt * 16 + q * 4 + r;
                float btp = S[mt][nt][r];
                float sd = pdi[mt][r] + pdj;
                float sg = pgi[mt][r] + pgj;
                float e2x = __expf(2.f * sd);
                float sln = 1.f - 2.f * __builtin_amdgcn_rcpf(e2x + 1.f);   // tanh(sd)
                float g = __builtin_amdgcn_rcpf(1.f + __expf(-sg));          // sigmoid(sg)
                float val = u_k * (g * btp + (1.f - g) * sln + b_k);
                if (SLAB) {
                    // permuted coalesced layout: pos = v*256 + tid, v = nt*8+mt*4+r
                    sdst[(nt * 8 + mt * 4 + r) * 256 + tid] = (_Float16)val;
                } else {
                    unsafeAtomicAdd(adst + (size_t)i * LL + j, val);
                }
            }
    }
}

// ---------- reduce: out[b][i][j] = sum_k slab[k][b][pos]; decode permutation ----------
__global__ void reduce_k(const _Float16* __restrict__ slab, float* __restrict__ out) {
    int idx = blockIdx.x * 256 + threadIdx.x;     // 0..131071
    int b = idx >> 12;
    int p4 = idx & 4095;
    int pos0 = p4 * 4;
    int v = pos0 >> 8, tid0 = pos0 & 255;
    int nt = v >> 3, mt = (v >> 2) & 1, r = v & 3;
    int wid = tid0 >> 6, q = (tid0 >> 4) & 3, ln0 = tid0 & 15;
    int i = wid * 32 + mt * 16 + q * 4 + r;
    int j0 = nt * 16 + ln0;

    float a0 = 0.f, a1 = 0.f, a2 = 0.f, a3 = 0.f;
    const _Float16* sp = slab + (size_t)b * 16384 + pos0;
#pragma unroll
    for (int k = 0; k < KDIM; ++k) {
        half4v h = *(const half4v*)(sp + (size_t)k * (NB * 16384));
        a0 += (float)h[0]; a1 += (float)h[1]; a2 += (float)h[2]; a3 += (float)h[3];
    }
    float4 rv; rv.x = a0; rv.y = a1; rv.z = a2; rv.w = a3;
    *(float4*)(out + (size_t)b * 16384 + i * 128 + j0) = rv;
}

extern "C" void kernel_launch(void* const* d_in, const int* in_sizes, int n_in,
                              void* d_out, int out_size, void* d_ws, size_t ws_size,
                              hipStream_t stream) {
    const float* e1 = (const float*)d_in[0];   // (32,128,300)
    const float* e2 = (const float*)d_in[1];   // (32,128,300)
    const float* Wb = (const float*)d_in[2];   // (50,300,300)
    const float* Wd = (const float*)d_in[3];   // (600,50)
    const float* Wg = (const float*)d_in[4];   // (600,50)
    const float* bg = (const float*)d_in[5];   // (50,)
    const float* bb = (const float*)d_in[6];   // (50,)
    const float* u  = (const float*)d_in[7];   // (50,1)
    float* out = (float*)d_out;                // (32,128,128,1)

    unsigned short* e1b = (unsigned short*)d_ws;                 // 1,310,720 elems
    unsigned short* e2b = e1b + 1310720;                         // 1,310,720 elems
    unsigned short* wbt = e2b + 1310720;                         // 5,120,000 elems
    float* pf  = (float*)((char*)d_ws + 15482880);
    float* p1d = pf;
    float* p1g = pf + 204800;
    float* p2d = pf + 409600;
    float* p2g = pf + 614400;                                    // end 18,759,680 B
    _Float16* slab = (_Float16*)((char*)d_ws + SLAB_OFF);        // 50x32x16384 halves

    prep_all<<<1012, 256, 0, stream>>>(e1, e2, Wb, Wd, Wg,
                                       e1b, e2b, wbt,
                                       p1d, p1g, p2d, p2g);

    if (ws_size >= WS_NEED) {
        grn_main<1><<<dim3(NB, KDIM), 256, 0, stream>>>(e1b, e2b, wbt,
                                                        p1d, p1g, p2d, p2g,
                                                        bg, bb, u, out, slab);
        reduce_k<<<512, 256, 0, stream>>>(slab, out);
    } else {
        hipMemsetAsync(d_out, 0, (size_t)out_size * sizeof(float), stream);
        grn_main<0><<<dim3(NB, KDIM), 256, 0, stream>>>(e1b, e2b, wbt,
                                                        p1d, p1g, p2d, p2g,
                                                        bg, bb, u, out, slab);
    }
}